// Round 12
// baseline (692.176 us; speedup 1.0000x reference)
//
#include <hip/hip_runtime.h>

#define N_NODES 50000
#define N_EDGES 800000
#define D 128
#define HEADS 8

typedef __attribute__((ext_vector_type(8))) short short8b;            // 8 bf16
typedef __attribute__((ext_vector_type(8))) unsigned short ushort8v;  // 16 B
typedef __attribute__((ext_vector_type(4))) float f32x4;

__device__ __forceinline__ unsigned short f2bf_rne(float f) {
    unsigned int u = __float_as_uint(f);
    u += 0x7FFFu + ((u >> 16) & 1u);   // round-to-nearest-even
    return (unsigned short)(u >> 16);
}
__device__ __forceinline__ float bf2f(unsigned short u) {
    return __uint_as_float(((unsigned int)u) << 16);
}

// DPP 16-lane row sum (4 VALU ops, no DS traffic)
template <int CTRL>
__device__ __forceinline__ float dpp_radd(float v) {
    int s = __builtin_amdgcn_update_dpp(0, __float_as_int(v), CTRL, 0xF, 0xF, true);
    return v + __int_as_float(s);
}
__device__ __forceinline__ float rowsum16(float v) {
    v = dpp_radd<0xB1>(v);    // quad_perm xor1
    v = dpp_radd<0x4E>(v);    // quad_perm xor2
    v = dpp_radd<0x141>(v);   // row_half_mirror
    v = dpp_radd<0x140>(v);   // row_mirror
    return v;
}

// ---------------- K1 (MFMA): hs/hr = bf16(nodes @ W + b), PERMUTED ----------
// Row layout: position p = li*8 + h holds col c = h*16 + li
#define K1_ROWS 256
__global__ __launch_bounds__(256, 3) void k_node_proj_mfma(
    const float* __restrict__ nodes,
    const float* __restrict__ Ws, const float* __restrict__ bs,
    const float* __restrict__ Wr, const float* __restrict__ br,
    unsigned short* __restrict__ hsb, unsigned short* __restrict__ hrb)
{
    __shared__ __align__(16) unsigned short WT[D][136];   // [col][k] 34816 B
    __shared__ __align__(16) unsigned short At[64][136];  // [row][k] 17408 B
    const int ntiles = (N_NODES + K1_ROWS - 1) / K1_ROWS;   // 196
    int bx = blockIdx.x;
    int proj = (bx >= ntiles) ? 1 : 0;
    int tile = proj ? (bx - ntiles) : bx;
    const float* W    = proj ? Wr : Ws;
    const float* bias = proj ? br : bs;
    unsigned short* outp = proj ? hrb : hsb;
    int t = threadIdx.x;
    int lane = t & 63;
    int wv = t >> 6;
    int lg = lane >> 4;
    int li = lane & 15;

    #pragma unroll 8
    for (int j = 0; j < 64; ++j) {
        int idx = t + 256 * j;     // k*128+c
        int k = idx >> 7, c = idx & 127;
        WT[c][k] = f2bf_rne(W[idx]);
    }
    float b_ct[8];
    #pragma unroll
    for (int ct = 0; ct < 8; ++ct) b_ct[ct] = bias[ct * 16 + li];

    #pragma unroll 1
    for (int sub = 0; sub < 4; ++sub) {
        int row0 = tile * K1_ROWS + sub * 64;
        if (row0 >= N_NODES) break;          // uniform
        __syncthreads();
        {   // stage 64 node rows -> bf16 LDS
            const float4* Nv = (const float4*)nodes;
            #pragma unroll
            for (int j = 0; j < 8; ++j) {
                int fi = t + 256 * j;
                int r = row0 + (fi >> 5);
                float4 v = make_float4(0.f, 0.f, 0.f, 0.f);
                if (r < N_NODES) v = Nv[(size_t)r * 32 + (fi & 31)];
                ushort4 b;
                b.x = f2bf_rne(v.x); b.y = f2bf_rne(v.y);
                b.z = f2bf_rne(v.z); b.w = f2bf_rne(v.w);
                *(ushort4*)&At[fi >> 5][(fi & 31) * 4] = b;
            }
        }
        __syncthreads();

        short8b afr[4];
        #pragma unroll
        for (int kb = 0; kb < 4; ++kb)
            afr[kb] = *(const short8b*)&At[wv * 16 + li][kb * 32 + lg * 8];

        f32x4 accs[8];
        #pragma unroll
        for (int ct = 0; ct < 8; ++ct) {
            f32x4 acc = {0.f, 0.f, 0.f, 0.f};
            #pragma unroll
            for (int kb = 0; kb < 4; ++kb) {
                short8b bfr = *(const short8b*)&WT[ct * 16 + li][kb * 32 + lg * 8];
                acc = __builtin_amdgcn_mfma_f32_16x16x32_bf16(afr[kb], bfr, acc, 0, 0, 0);
            }
            accs[ct] = acc;
        }
        #pragma unroll
        for (int j = 0; j < 4; ++j) {
            int r = row0 + wv * 16 + lg * 4 + j;
            if (r < N_NODES) {
                uint4 w;
                w.x = (unsigned)f2bf_rne(accs[0][j] + b_ct[0])
                    | ((unsigned)f2bf_rne(accs[1][j] + b_ct[1]) << 16);
                w.y = (unsigned)f2bf_rne(accs[2][j] + b_ct[2])
                    | ((unsigned)f2bf_rne(accs[3][j] + b_ct[3]) << 16);
                w.z = (unsigned)f2bf_rne(accs[4][j] + b_ct[4])
                    | ((unsigned)f2bf_rne(accs[5][j] + b_ct[5]) << 16);
                w.w = (unsigned)f2bf_rne(accs[6][j] + b_ct[6])
                    | ((unsigned)f2bf_rne(accs[7][j] + b_ct[7]) << 16);
                *(uint4*)&outp[(size_t)r * D + li * 8] = w;   // 16B coalesced
            }
        }
    }
}

// ------------------------- CSR build ----------------------------------------
__global__ __launch_bounds__(256) void k_hist(
    const int* __restrict__ receivers, int* __restrict__ deg)
{
    int i = blockIdx.x * 256 + threadIdx.x;
    if (i < N_EDGES) atomicAdd(&deg[receivers[i]], 1);
}

#define SCAN_CHUNK 49
__global__ __launch_bounds__(1024) void k_scan(
    const int* __restrict__ deg, int* __restrict__ rowptr, int* __restrict__ cursor)
{
    __shared__ int sm[1024];
    int t = threadIdx.x;
    int base = t * SCAN_CHUNK;
    int lsum = 0;
    #pragma unroll 4
    for (int i = 0; i < SCAN_CHUNK; ++i) {
        int idx = base + i;
        if (idx < N_NODES) lsum += deg[idx];
    }
    sm[t] = lsum;
    __syncthreads();
    for (int off = 1; off < 1024; off <<= 1) {
        int v = (t >= off) ? sm[t - off] : 0;
        __syncthreads();
        sm[t] += v;
        __syncthreads();
    }
    int run = (t > 0) ? sm[t - 1] : 0;
    for (int i = 0; i < SCAN_CHUNK; ++i) {
        int idx = base + i;
        if (idx < N_NODES) {
            rowptr[idx] = run;
            cursor[idx] = run;
            run += deg[idx];
        }
    }
    if (t == 1023) rowptr[N_NODES] = sm[1023];
}

__global__ __launch_bounds__(256) void k_fill(
    const int* __restrict__ receivers, const int* __restrict__ senders,
    int* __restrict__ cursor,
    int* __restrict__ eids, int* __restrict__ s_csr)
{
    int i = blockIdx.x * 256 + threadIdx.x;
    if (i < N_EDGES) {
        int r = receivers[i];
        int pos = atomicAdd(&cursor[r], 1);
        eids[pos]  = i;
        s_csr[pos] = senders[i];
    }
}

// ------- K2' FUSED: per-node edge GEMM + softmax + weighted sum -> out ------
// One wave per node. Edges tiled 16 at a time (avg deg = 16 -> ~1 tile).
__global__ __launch_bounds__(256, 3) void k_fused_attn(
    const float* __restrict__ edges,
    const int* __restrict__ rowptr, const int* __restrict__ eids,
    const int* __restrict__ s_csr,
    const float* __restrict__ We, const float* __restrict__ be,
    const float* __restrict__ a,
    const unsigned short* __restrict__ hsb, const unsigned short* __restrict__ hrb,
    float* __restrict__ out)
{
    __shared__ __align__(16) unsigned short WeT[D][136];    // [col][k] 34816 B
    __shared__ __align__(16) unsigned short Et[64][136];    // [edge][k] 17408 B
    __shared__ float obuf[4][128];                          // 2048 B
    int t = threadIdx.x;
    int lane = t & 63;
    int wv = t >> 6;
    int lg = lane >> 4;
    int li = lane & 15;

    #pragma unroll 8
    for (int j = 0; j < 64; ++j) {
        int idx = t + 256 * j;
        int k = idx >> 7, c = idx & 127;
        WeT[c][k] = f2bf_rne(We[idx]);
    }
    float a_h[HEADS], be_h[HEADS];
    #pragma unroll
    for (int h = 0; h < HEADS; ++h) {
        a_h[h]  = a[h * 16 + li];
        be_h[h] = be[h * 16 + li];
    }
    __syncthreads();   // WeT ready; the ONLY block barrier

    int node = blockIdx.x * 4 + wv;           // 50000 % 4 == 0
    int beg = rowptr[node], end = rowptr[node + 1];

    // receiver projection: ONE 16B load (all 8 heads at col li)
    ushort8v g_hr = *(const ushort8v*)(hrb + (size_t)node * D + li * 8);

    float den[8], oac[8];
    #pragma unroll
    for (int h = 0; h < HEADS; ++h) { den[h] = 0.f; oac[h] = 0.f; }

    for (int j0 = beg; j0 < end; j0 += 16) {
        int cnt = end - j0;                   // valid edges this tile (>=1)

        // stage up to 16 edge rows -> bf16 LDS (coalesced 512B rows)
        {
            const float4* Ev = (const float4*)edges;
            #pragma unroll
            for (int j = 0; j < 8; ++j) {
                int fi = lane + 64 * j;        // 0..511
                int rloc = fi >> 5;            // 0..15
                if (rloc < cnt) {
                    int e = eids[j0 + rloc];   // broadcast
                    float4 v = Ev[(size_t)e * 32 + (fi & 31)];
                    ushort4 b;
                    b.x = f2bf_rne(v.x); b.y = f2bf_rne(v.y);
                    b.z = f2bf_rne(v.z); b.w = f2bf_rne(v.w);
                    *(ushort4*)&Et[wv * 16 + rloc][(fi & 31) * 4] = b;
                }
            }
        }

        // sender ids + hs gathers for this lane's 4 edge slots (clamped)
        int sj[4];
        #pragma unroll
        for (int j = 0; j < 4; ++j) {
            int p = j0 + lg * 4 + j;
            sj[j] = s_csr[p < end ? p : (end - 1)];
        }
        ushort8v g_hs[4];
        #pragma unroll
        for (int j = 0; j < 4; ++j)
            g_hs[j] = *(const ushort8v*)(hsb + (size_t)sj[j] * D + li * 8);

        // intra-wave LDS write->read fence
        asm volatile("s_waitcnt lgkmcnt(0)" ::: "memory");
        __builtin_amdgcn_sched_barrier(0);

        short8b afr[4];
        #pragma unroll
        for (int kb = 0; kb < 4; ++kb)
            afr[kb] = *(const short8b*)&Et[wv * 16 + li][kb * 32 + lg * 8];

        #pragma unroll
        for (int h = 0; h < HEADS; ++h) {
            f32x4 acc = {0.f, 0.f, 0.f, 0.f};
            #pragma unroll
            for (int kb = 0; kb < 4; ++kb) {
                short8b bfr = *(const short8b*)&WeT[h * 16 + li][kb * 32 + lg * 8];
                acc = __builtin_amdgcn_mfma_f32_16x16x32_bf16(afr[kb], bfr, acc, 0, 0, 0);
            }
            #pragma unroll
            for (int j = 0; j < 4; ++j) {
                float x = acc[j] + be_h[h] + bf2f(g_hs[j][h]) + bf2f(g_hr[h]);
                x = fmaxf(x, 0.01f * x);              // leaky relu
                float pr = rowsum16(x * a_h[h]);      // logit for edge lg*4+j
                bool valid = (lg * 4 + j) < cnt;
                float e_ = valid ? __expf(pr) : 0.f;  // masked exp
                den[h] += e_;                          // wave-local denom part
                oac[h] += e_ * bf2f(g_hs[j][h]);       // message part (reuses g_hs!)
            }
        }
        __builtin_amdgcn_wave_barrier();
    }

    // cross-row reduce (sum the 4 lg groups) + normalize
    float wn[8];
    #pragma unroll
    for (int h = 0; h < HEADS; ++h) {
        float d = den[h];
        d += __shfl_xor(d, 16); d += __shfl_xor(d, 32);
        float o = oac[h];
        o += __shfl_xor(o, 16); o += __shfl_xor(o, 32);
        wn[h] = (end > beg && d != 0.f) ? (o / d) : 0.f;
    }
    // lane (lg,li) owns heads 2lg, 2lg+1 -> obuf cols 32lg+li, 32lg+16+li
    float wa = (lg == 0) ? wn[0] : (lg == 1) ? wn[2] : (lg == 2) ? wn[4] : wn[6];
    float wb = (lg == 0) ? wn[1] : (lg == 1) ? wn[3] : (lg == 2) ? wn[5] : wn[7];
    obuf[wv][32 * lg + li]      = wa;
    obuf[wv][32 * lg + 16 + li] = wb;
    asm volatile("s_waitcnt lgkmcnt(0)" ::: "memory");
    __builtin_amdgcn_sched_barrier(0);
    float2 o2 = *(const float2*)&obuf[wv][2 * lane];
    *(float2*)&out[(size_t)node * D + 2 * lane] = o2;   // 512B coalesced
}

extern "C" void kernel_launch(void* const* d_in, const int* in_sizes, int n_in,
                              void* d_out, int out_size, void* d_ws, size_t ws_size,
                              hipStream_t stream) {
    const float* nodes     = (const float*)d_in[0];
    const float* edges     = (const float*)d_in[1];
    const int*   senders   = (const int*)d_in[2];
    const int*   receivers = (const int*)d_in[3];
    const float* Ws = (const float*)d_in[4];
    const float* bs = (const float*)d_in[5];
    const float* Wr = (const float*)d_in[6];
    const float* br = (const float*)d_in[7];
    const float* We = (const float*)d_in[8];
    const float* be = (const float*)d_in[9];
    const float* a  = (const float*)d_in[10];
    float* out = (float*)d_out;

    unsigned short* hsb = (unsigned short*)d_ws;          // 6.4M bf16 (permuted)
    unsigned short* hrb = hsb + (size_t)N_NODES * D;      // 6.4M bf16 (permuted)
    int* deg    = (int*)(hrb + (size_t)N_NODES * D);      // 50000
    int* rowptr = deg + N_NODES;                          // 50001
    int* cursor = rowptr + N_NODES + 1;                   // 50000
    int* eids   = cursor + N_NODES;                       // 800000
    int* s_csr  = eids + N_EDGES;                         // 800000

    (void)hipMemsetAsync(deg, 0, N_NODES * sizeof(int), stream);
    k_hist<<<N_EDGES / 256, 256, 0, stream>>>(receivers, deg);
    k_scan<<<1, 1024, 0, stream>>>(deg, rowptr, cursor);
    k_fill<<<N_EDGES / 256, 256, 0, stream>>>(receivers, senders, cursor,
                                              eids, s_csr);
    int ntiles_n = (N_NODES + K1_ROWS - 1) / K1_ROWS;
    k_node_proj_mfma<<<ntiles_n * 2, 256, 0, stream>>>(nodes, Ws, bs, Wr, br, hsb, hrb);
    k_fused_attn<<<N_NODES / 4, 256, 0, stream>>>(edges, rowptr, eids, s_csr,
                                                  We, be, a, hsb, hrb, out);
}

// Round 13
// 507.784 us; speedup vs baseline: 1.3631x; 1.3631x over previous
//
#include <hip/hip_runtime.h>

#define N_NODES 50000
#define N_EDGES 800000
#define D 128
#define HEADS 8

typedef __attribute__((ext_vector_type(8))) short short8b;  // 8 bf16 (4 VGPRs)
typedef __attribute__((ext_vector_type(4))) float f32x4;

__device__ __forceinline__ unsigned short f2bf_rne(float f) {
    unsigned int u = __float_as_uint(f);
    u += 0x7FFFu + ((u >> 16) & 1u);   // round-to-nearest-even
    return (unsigned short)(u >> 16);
}
__device__ __forceinline__ float bf2f(unsigned short u) {
    return __uint_as_float(((unsigned int)u) << 16);
}

// ---------------- K1 (MFMA): hs/hr = bf16(nodes @ W + b) --------------------
#define K1_ROWS 256
__global__ __launch_bounds__(256, 3) void k_node_proj_mfma(
    const float* __restrict__ nodes,
    const float* __restrict__ Ws, const float* __restrict__ bs,
    const float* __restrict__ Wr, const float* __restrict__ br,
    unsigned short* __restrict__ hsb, unsigned short* __restrict__ hrb)
{
    __shared__ __align__(16) unsigned short WT[D][136];   // [col][k] 34816 B
    __shared__ __align__(16) unsigned short At[64][136];  // [row][k] 17408 B
    const int ntiles = (N_NODES + K1_ROWS - 1) / K1_ROWS;   // 196
    int bx = blockIdx.x;
    int proj = (bx >= ntiles) ? 1 : 0;
    int tile = proj ? (bx - ntiles) : bx;
    const float* W    = proj ? Wr : Ws;
    const float* bias = proj ? br : bs;
    unsigned short* outp = proj ? hrb : hsb;
    int t = threadIdx.x;
    int lane = t & 63;
    int wv = t >> 6;
    int lg = lane >> 4;
    int li = lane & 15;

    #pragma unroll 8
    for (int j = 0; j < 64; ++j) {
        int idx = t + 256 * j;     // k*128+c
        int k = idx >> 7, c = idx & 127;
        WT[c][k] = f2bf_rne(W[idx]);
    }
    float b_ct[8];
    #pragma unroll
    for (int ct = 0; ct < 8; ++ct) b_ct[ct] = bias[ct * 16 + li];

    #pragma unroll 1
    for (int sub = 0; sub < 4; ++sub) {
        int row0 = tile * K1_ROWS + sub * 64;
        if (row0 >= N_NODES) break;          // uniform
        __syncthreads();
        {   // stage 64 node rows -> bf16 LDS
            const float4* Nv = (const float4*)nodes;
            #pragma unroll
            for (int j = 0; j < 8; ++j) {
                int fi = t + 256 * j;
                int r = row0 + (fi >> 5);
                float4 v = make_float4(0.f, 0.f, 0.f, 0.f);
                if (r < N_NODES) v = Nv[(size_t)r * 32 + (fi & 31)];
                ushort4 b;
                b.x = f2bf_rne(v.x); b.y = f2bf_rne(v.y);
                b.z = f2bf_rne(v.z); b.w = f2bf_rne(v.w);
                *(ushort4*)&At[fi >> 5][(fi & 31) * 4] = b;
            }
        }
        __syncthreads();

        short8b afr[4];
        #pragma unroll
        for (int kb = 0; kb < 4; ++kb)
            afr[kb] = *(const short8b*)&At[wv * 16 + li][kb * 32 + lg * 8];

        #pragma unroll
        for (int ct = 0; ct < 8; ++ct) {
            f32x4 acc = {0.f, 0.f, 0.f, 0.f};
            #pragma unroll
            for (int kb = 0; kb < 4; ++kb) {
                short8b bfr = *(const short8b*)&WT[ct * 16 + li][kb * 32 + lg * 8];
                acc = __builtin_amdgcn_mfma_f32_16x16x32_bf16(afr[kb], bfr, acc, 0, 0, 0);
            }
            #pragma unroll
            for (int j = 0; j < 4; ++j) {
                int r = row0 + wv * 16 + lg * 4 + j;
                if (r < N_NODES)
                    outp[(size_t)r * D + ct * 16 + li] = f2bf_rne(acc[j] + b_ct[ct]);
            }
        }
    }
}

// ------------------------- CSR build (runs before K2) ------------------------
__global__ __launch_bounds__(256) void k_hist(
    const int* __restrict__ receivers, int* __restrict__ deg)
{
    int i = blockIdx.x * 256 + threadIdx.x;
    if (i < N_EDGES) atomicAdd(&deg[receivers[i]], 1);
}

#define SCAN_CHUNK 49
__global__ __launch_bounds__(1024) void k_scan(
    const int* __restrict__ deg, int* __restrict__ rowptr, int* __restrict__ cursor)
{
    __shared__ int sm[1024];
    int t = threadIdx.x;
    int base = t * SCAN_CHUNK;
    int lsum = 0;
    #pragma unroll 4
    for (int i = 0; i < SCAN_CHUNK; ++i) {
        int idx = base + i;
        if (idx < N_NODES) lsum += deg[idx];
    }
    sm[t] = lsum;
    __syncthreads();
    for (int off = 1; off < 1024; off <<= 1) {
        int v = (t >= off) ? sm[t - off] : 0;
        __syncthreads();
        sm[t] += v;
        __syncthreads();
    }
    int run = (t > 0) ? sm[t - 1] : 0;
    for (int i = 0; i < SCAN_CHUNK; ++i) {
        int idx = base + i;
        if (idx < N_NODES) {
            rowptr[idx] = run;
            cursor[idx] = run;
            run += deg[idx];
        }
    }
    if (t == 1023) rowptr[N_NODES] = sm[1023];
}

__global__ __launch_bounds__(256) void k_fill(
    const int* __restrict__ receivers, const int* __restrict__ senders,
    int* __restrict__ cursor,
    int* __restrict__ eids, int* __restrict__ s_csr, int* __restrict__ r_csr)
{
    int i = blockIdx.x * 256 + threadIdx.x;
    if (i < N_EDGES) {
        int r = receivers[i];
        int pos = atomicAdd(&cursor[r], 1);
        eids[pos]  = i;
        s_csr[pos] = senders[i];
        r_csr[pos] = r;
    }
}

// ------- K2 (MFMA bf16, CSR order, wave-local, T14 row prefetch) -------------
// Persistent register buffer ea[8] holds the CURRENT tile's edge rows; the
// NEXT tile's rows are loaded after the LDS fence so they stay in flight
// through the MFMA+epilogue (younger vmem => waiting on gathers won't drain).
#define BLK_E 64
__global__ __launch_bounds__(256, 3) void k_edge_logits_mfma(
    const float* __restrict__ edges,
    const int* __restrict__ eids, const int* __restrict__ s_csr,
    const int* __restrict__ r_csr,
    const float* __restrict__ We, const float* __restrict__ be,
    const float* __restrict__ a,
    const unsigned short* __restrict__ hsb, const unsigned short* __restrict__ hrb,
    float* __restrict__ ex)
{
    __shared__ __align__(16) unsigned short WeT[D][136];    // [col][k] 34816 B
    __shared__ __align__(16) unsigned short Et[BLK_E][136]; // [edge][k] 17408 B
    int t = threadIdx.x;
    int lane = t & 63;
    int wv = t >> 6;
    int lg = lane >> 4;
    int li = lane & 15;

    #pragma unroll 8
    for (int j = 0; j < 64; ++j) {
        int idx = t + 256 * j;
        int k = idx >> 7, c = idx & 127;
        WeT[c][k] = f2bf_rne(We[idx]);
    }
    float a_h[HEADS], be_h[HEADS];
    #pragma unroll
    for (int h = 0; h < HEADS; ++h) {
        a_h[h]  = a[h * 16 + li];
        be_h[h] = be[h * 16 + li];
    }
    int jm = li & 3;
    __syncthreads();   // WeT ready; the ONLY block barrier

    const int ntiles = N_EDGES / BLK_E;   // 12500
    const float4* Ev = (const float4*)edges;

    int tile = blockIdx.x;
    float4 ea[8];   // current tile's edge rows (reg-staged)
    if (tile < ntiles) {   // prologue: load first tile's rows
        int pb = tile * BLK_E + wv * 16;
        #pragma unroll
        for (int j = 0; j < 8; ++j) {
            int fi = lane + 64 * j;
            int e = eids[pb + (fi >> 5)];
            ea[j] = Ev[(size_t)e * 32 + (fi & 31)];
        }
    }

    for (; tile < ntiles; tile += gridDim.x) {
        int pbase = tile * BLK_E + wv * 16;
        int ntile = tile + gridDim.x;
        bool has_next = (ntile < ntiles);

        // (1) next tile's eids FIRST (oldest vmem -> cheap to wait on later)
        int en[8];
        if (has_next) {
            int npb = ntile * BLK_E + wv * 16;
            #pragma unroll
            for (int j = 0; j < 8; ++j)
                en[j] = eids[npb + ((lane + 64 * j) >> 5)];
        }

        // (2) current-tile gathers (hr mostly L1-local in CSR order)
        int sj[4], rj[4];
        #pragma unroll
        for (int j = 0; j < 4; ++j) {
            sj[j] = s_csr[pbase + lg * 4 + j];
            rj[j] = r_csr[pbase + lg * 4 + j];
        }
        unsigned short g_hs[4][HEADS], g_hr[4][HEADS];
        #pragma unroll
        for (int j = 0; j < 4; ++j) {
            const unsigned short* hsrow = hsb + (size_t)sj[j] * D + li;
            const unsigned short* hrrow = hrb + (size_t)rj[j] * D + li;
            #pragma unroll
            for (int h = 0; h < HEADS; ++h) {
                g_hs[j][h] = hsrow[h * 16];
                g_hr[j][h] = hrrow[h * 16];
            }
        }

        // (3) cvt + ds_write current rows from registers
        #pragma unroll
        for (int j = 0; j < 8; ++j) {
            int fi = lane + 64 * j;
            ushort4 b;
            b.x = f2bf_rne(ea[j].x); b.y = f2bf_rne(ea[j].y);
            b.z = f2bf_rne(ea[j].z); b.w = f2bf_rne(ea[j].w);
            *(ushort4*)&Et[wv * 16 + (fi >> 5)][(fi & 31) * 4] = b;
        }

        // (4) intra-wave LDS write->read fence
        asm volatile("s_waitcnt lgkmcnt(0)" ::: "memory");
        __builtin_amdgcn_sched_barrier(0);

        // (5) A fragments (after this, Et is dead for this tile)
        short8b afr[4];
        #pragma unroll
        for (int kb = 0; kb < 4; ++kb)
            afr[kb] = *(const short8b*)&Et[wv * 16 + li][kb * 32 + lg * 8];

        // (6) prefetch NEXT tile's rows -> in flight through compute
        if (has_next) {
            #pragma unroll
            for (int j = 0; j < 8; ++j)
                ea[j] = Ev[(size_t)en[j] * 32 + ((lane + 64 * j) & 31)];
        }

        // (7) compute: 8 heads x (4 MFMA + leaky + logit + reduce + exp)
        #pragma unroll
        for (int h = 0; h < HEADS; ++h) {
            f32x4 acc = {0.f, 0.f, 0.f, 0.f};
            #pragma unroll
            for (int kb = 0; kb < 4; ++kb) {
                short8b bfr = *(const short8b*)&WeT[h * 16 + li][kb * 32 + lg * 8];
                acc = __builtin_amdgcn_mfma_f32_16x16x32_bf16(afr[kb], bfr, acc, 0, 0, 0);
            }
            float p[4];
            #pragma unroll
            for (int j = 0; j < 4; ++j) {
                float x = acc[j] + be_h[h] + bf2f(g_hs[j][h]) + bf2f(g_hr[j][h]);
                x = x > 0.f ? x : 0.01f * x;
                p[j] = x * a_h[h];
            }
            #pragma unroll
            for (int j = 0; j < 4; ++j) {
                p[j] += __shfl_xor(p[j], 1);
                p[j] += __shfl_xor(p[j], 2);
            }
            float q = (jm & 1) ? ((jm & 2) ? p[3] : p[1])
                               : ((jm & 2) ? p[2] : p[0]);
            q += __shfl_xor(q, 4);
            q += __shfl_xor(q, 8);
            float e_ = __expf(q);
            if (li < 4) {
                int pos = pbase + lg * 4 + li;
                ex[(size_t)pos * HEADS + h] = e_;    // CSR-contiguous write
            }
        }
        __builtin_amdgcn_wave_barrier();
    }
}

// ---------- K3: per-node gather; s_csr/ex contiguous, hs random -------------
__global__ __launch_bounds__(256) void k_gather_out(
    const int* __restrict__ rowptr, const int* __restrict__ s_csr,
    const unsigned short* __restrict__ hsb, const float* __restrict__ ex,
    float* __restrict__ out)
{
    int r = blockIdx.x * 4 + (threadIdx.x >> 6);
    int l = threadIdx.x & 63;
    int h = l >> 3;
    int beg = rowptr[r], end = rowptr[r + 1];

    float2 acc = make_float2(0.f, 0.f);
    float dsum = 0.f;
    for (int j0 = beg; j0 < end; j0 += 16) {
        int cnt = end - j0;
        int s[16]; float w[16];
        #pragma unroll
        for (int q = 0; q < 16; ++q)
            if (q < cnt) { s[q] = s_csr[j0 + q]; w[q] = ex[(size_t)(j0 + q) * HEADS + h]; }
        #pragma unroll
        for (int q = 0; q < 16; ++q)
            if (q < cnt) {
                ushort2 hv = *(const ushort2*)&hsb[(size_t)s[q] * D + 2 * l];
                acc.x += w[q] * bf2f(hv.x);
                acc.y += w[q] * bf2f(hv.y);
                dsum  += w[q];
            }
    }
    float inv = (end > beg && dsum != 0.f) ? (1.0f / dsum) : 0.f;
    acc.x *= inv; acc.y *= inv;
    *(float2*)&out[(size_t)r * D + 2 * l] = acc;
}

extern "C" void kernel_launch(void* const* d_in, const int* in_sizes, int n_in,
                              void* d_out, int out_size, void* d_ws, size_t ws_size,
                              hipStream_t stream) {
    const float* nodes     = (const float*)d_in[0];
    const float* edges     = (const float*)d_in[1];
    const int*   senders   = (const int*)d_in[2];
    const int*   receivers = (const int*)d_in[3];
    const float* Ws = (const float*)d_in[4];
    const float* bs = (const float*)d_in[5];
    const float* Wr = (const float*)d_in[6];
    const float* br = (const float*)d_in[7];
    const float* We = (const float*)d_in[8];
    const float* be = (const float*)d_in[9];
    const float* a  = (const float*)d_in[10];
    float* out = (float*)d_out;

    unsigned short* hsb = (unsigned short*)d_ws;          // 6.4M bf16
    unsigned short* hrb = hsb + (size_t)N_NODES * D;      // 6.4M bf16
    float* ex   = (float*)(hrb + (size_t)N_NODES * D);    // 6.4M f32 (CSR order)
    int* deg    = (int*)(ex + (size_t)N_EDGES * HEADS);   // 50000
    int* rowptr = deg + N_NODES;                          // 50001
    int* cursor = rowptr + N_NODES + 1;                   // 50000
    int* eids   = cursor + N_NODES;                       // 800000
    int* s_csr  = eids + N_EDGES;                         // 800000
    int* r_csr  = s_csr + N_EDGES;                        // 800000

    (void)hipMemsetAsync(deg, 0, N_NODES * sizeof(int), stream);
    k_hist<<<N_EDGES / 256, 256, 0, stream>>>(receivers, deg);
    k_scan<<<1, 1024, 0, stream>>>(deg, rowptr, cursor);
    k_fill<<<N_EDGES / 256, 256, 0, stream>>>(receivers, senders, cursor,
                                              eids, s_csr, r_csr);
    int ntiles_n = (N_NODES + K1_ROWS - 1) / K1_ROWS;
    k_node_proj_mfma<<<ntiles_n * 2, 256, 0, stream>>>(nodes, Ws, bs, Wr, br, hsb, hrb);
    k_edge_logits_mfma<<<2048, 256, 0, stream>>>(edges, eids, s_csr, r_csr,
                                                 We, be, a, hsb, hrb, ex);
    k_gather_out<<<N_NODES / 4, 256, 0, stream>>>(rowptr, s_csr, hsb, ex, out);
}

// Round 14
// 505.080 us; speedup vs baseline: 1.3704x; 1.0054x over previous
//
#include <hip/hip_runtime.h>

#define N_NODES 50000
#define N_EDGES 800000
#define D 128
#define HEADS 8

typedef __attribute__((ext_vector_type(8))) short short8b;  // 8 bf16 (4 VGPRs)
typedef __attribute__((ext_vector_type(4))) float f32x4;

__device__ __forceinline__ unsigned short f2bf_rne(float f) {
    unsigned int u = __float_as_uint(f);
    u += 0x7FFFu + ((u >> 16) & 1u);   // round-to-nearest-even
    return (unsigned short)(u >> 16);
}
__device__ __forceinline__ float bf2f(unsigned short u) {
    return __uint_as_float(((unsigned int)u) << 16);
}

// ---------------- K1 (MFMA): hs/hr = bf16(nodes @ W + b) --------------------
#define K1_ROWS 256
__global__ __launch_bounds__(256, 3) void k_node_proj_mfma(
    const float* __restrict__ nodes,
    const float* __restrict__ Ws, const float* __restrict__ bs,
    const float* __restrict__ Wr, const float* __restrict__ br,
    unsigned short* __restrict__ hsb, unsigned short* __restrict__ hrb)
{
    __shared__ __align__(16) unsigned short WT[D][136];   // [col][k] 34816 B
    __shared__ __align__(16) unsigned short At[64][136];  // [row][k] 17408 B
    const int ntiles = (N_NODES + K1_ROWS - 1) / K1_ROWS;   // 196
    int bx = blockIdx.x;
    int proj = (bx >= ntiles) ? 1 : 0;
    int tile = proj ? (bx - ntiles) : bx;
    const float* W    = proj ? Wr : Ws;
    const float* bias = proj ? br : bs;
    unsigned short* outp = proj ? hrb : hsb;
    int t = threadIdx.x;
    int lane = t & 63;
    int wv = t >> 6;
    int lg = lane >> 4;
    int li = lane & 15;

    #pragma unroll 8
    for (int j = 0; j < 64; ++j) {
        int idx = t + 256 * j;     // k*128+c
        int k = idx >> 7, c = idx & 127;
        WT[c][k] = f2bf_rne(W[idx]);
    }
    float b_ct[8];
    #pragma unroll
    for (int ct = 0; ct < 8; ++ct) b_ct[ct] = bias[ct * 16 + li];

    #pragma unroll 1
    for (int sub = 0; sub < 4; ++sub) {
        int row0 = tile * K1_ROWS + sub * 64;
        if (row0 >= N_NODES) break;          // uniform
        __syncthreads();
        {   // stage 64 node rows -> bf16 LDS
            const float4* Nv = (const float4*)nodes;
            #pragma unroll
            for (int j = 0; j < 8; ++j) {
                int fi = t + 256 * j;
                int r = row0 + (fi >> 5);
                float4 v = make_float4(0.f, 0.f, 0.f, 0.f);
                if (r < N_NODES) v = Nv[(size_t)r * 32 + (fi & 31)];
                ushort4 b;
                b.x = f2bf_rne(v.x); b.y = f2bf_rne(v.y);
                b.z = f2bf_rne(v.z); b.w = f2bf_rne(v.w);
                *(ushort4*)&At[fi >> 5][(fi & 31) * 4] = b;
            }
        }
        __syncthreads();

        short8b afr[4];
        #pragma unroll
        for (int kb = 0; kb < 4; ++kb)
            afr[kb] = *(const short8b*)&At[wv * 16 + li][kb * 32 + lg * 8];

        #pragma unroll
        for (int ct = 0; ct < 8; ++ct) {
            f32x4 acc = {0.f, 0.f, 0.f, 0.f};
            #pragma unroll
            for (int kb = 0; kb < 4; ++kb) {
                short8b bfr = *(const short8b*)&WT[ct * 16 + li][kb * 32 + lg * 8];
                acc = __builtin_amdgcn_mfma_f32_16x16x32_bf16(afr[kb], bfr, acc, 0, 0, 0);
            }
            #pragma unroll
            for (int j = 0; j < 4; ++j) {
                int r = row0 + wv * 16 + lg * 4 + j;
                if (r < N_NODES)
                    outp[(size_t)r * D + ct * 16 + li] = f2bf_rne(acc[j] + b_ct[ct]);
            }
        }
    }
}

// ------------------------- CSR build (runs before K2) ------------------------
__global__ __launch_bounds__(256) void k_hist(
    const int* __restrict__ receivers, int* __restrict__ deg)
{
    int i = blockIdx.x * 256 + threadIdx.x;
    if (i < N_EDGES) atomicAdd(&deg[receivers[i]], 1);
}

#define SCAN_CHUNK 49
__global__ __launch_bounds__(1024) void k_scan(
    const int* __restrict__ deg, int* __restrict__ rowptr, int* __restrict__ cursor)
{
    __shared__ int sm[1024];
    int t = threadIdx.x;
    int base = t * SCAN_CHUNK;
    int lsum = 0;
    #pragma unroll 4
    for (int i = 0; i < SCAN_CHUNK; ++i) {
        int idx = base + i;
        if (idx < N_NODES) lsum += deg[idx];
    }
    sm[t] = lsum;
    __syncthreads();
    for (int off = 1; off < 1024; off <<= 1) {
        int v = (t >= off) ? sm[t - off] : 0;
        __syncthreads();
        sm[t] += v;
        __syncthreads();
    }
    int run = (t > 0) ? sm[t - 1] : 0;
    for (int i = 0; i < SCAN_CHUNK; ++i) {
        int idx = base + i;
        if (idx < N_NODES) {
            rowptr[idx] = run;
            cursor[idx] = run;
            run += deg[idx];
        }
    }
    if (t == 1023) rowptr[N_NODES] = sm[1023];
}

// packed CSR record: one 16B scattered write per edge (1 cache line, not 3)
__global__ __launch_bounds__(256) void k_fill(
    const int* __restrict__ receivers, const int* __restrict__ senders,
    int* __restrict__ cursor, int4* __restrict__ csr4)
{
    int i = blockIdx.x * 256 + threadIdx.x;
    if (i < N_EDGES) {
        int r = receivers[i];
        int pos = atomicAdd(&cursor[r], 1);
        csr4[pos] = make_int4(i, senders[i], r, 0);
    }
}

// ------- K2 (MFMA bf16, CSR order, wave-local, 8-wave blocks) ----------------
// 512 threads share ONE WeT (LDS 69.6KB -> 2 blocks/CU = 16 waves/CU, vs 12).
// Wave-local staging exactly as round-8 best (no cross-tile reg prefetch).
#define BLK_E 128
__global__ __launch_bounds__(512, 4) void k_edge_logits_mfma(
    const float* __restrict__ edges,
    const int4* __restrict__ csr4,
    const float* __restrict__ We, const float* __restrict__ be,
    const float* __restrict__ a,
    const unsigned short* __restrict__ hsb, const unsigned short* __restrict__ hrb,
    float* __restrict__ ex)
{
    __shared__ __align__(16) unsigned short WeT[D][136];     // [col][k] 34816 B
    __shared__ __align__(16) unsigned short Et[BLK_E][136];  // [edge][k] 34816 B
    int t = threadIdx.x;
    int lane = t & 63;
    int wv = t >> 6;      // wave 0..7
    int lg = lane >> 4;
    int li = lane & 15;

    #pragma unroll 4
    for (int j = 0; j < 32; ++j) {
        int idx = t + 512 * j;     // 0..16383 = k*128+c
        int k = idx >> 7, c = idx & 127;
        WeT[c][k] = f2bf_rne(We[idx]);
    }
    float a_h[HEADS], be_h[HEADS];
    #pragma unroll
    for (int h = 0; h < HEADS; ++h) {
        a_h[h]  = a[h * 16 + li];
        be_h[h] = be[h * 16 + li];
    }
    int jm = li & 3;
    __syncthreads();   // WeT ready; the ONLY block barrier

    const int ntiles = N_EDGES / BLK_E;   // 6250
    const float4* Ev = (const float4*)edges;

    for (int tile = blockIdx.x; tile < ntiles; tile += gridDim.x) {
        int pbase = tile * BLK_E + wv * 16;   // this wave's 16 CSR rows

        // stage this wave's 16 edge rows -> bf16 LDS (coalesced 512B rows)
        #pragma unroll
        for (int j = 0; j < 8; ++j) {
            int fi = lane + 64 * j;        // 0..511
            int rloc = fi >> 5;            // 0..15
            int e = csr4[pbase + rloc].x;  // broadcast (L1)
            float4 v = Ev[(size_t)e * 32 + (fi & 31)];
            ushort4 b;
            b.x = f2bf_rne(v.x); b.y = f2bf_rne(v.y);
            b.z = f2bf_rne(v.z); b.w = f2bf_rne(v.w);
            *(ushort4*)&Et[wv * 16 + rloc][(fi & 31) * 4] = b;
        }

        // independent vmem while LDS writes drain
        int sj[4], rj[4];
        #pragma unroll
        for (int j = 0; j < 4; ++j) {
            int4 rec = csr4[pbase + lg * 4 + j];
            sj[j] = rec.y;
            rj[j] = rec.z;
        }
        unsigned short g_hs[4][HEADS], g_hr[4][HEADS];
        #pragma unroll
        for (int j = 0; j < 4; ++j) {
            const unsigned short* hsrow = hsb + (size_t)sj[j] * D + li;
            const unsigned short* hrrow = hrb + (size_t)rj[j] * D + li;
            #pragma unroll
            for (int h = 0; h < HEADS; ++h) {
                g_hs[j][h] = hsrow[h * 16];
                g_hr[j][h] = hrrow[h * 16];
            }
        }

        // intra-wave LDS write->read fence (no block barrier needed)
        asm volatile("s_waitcnt lgkmcnt(0)" ::: "memory");
        __builtin_amdgcn_sched_barrier(0);

        short8b afr[4];
        #pragma unroll
        for (int kb = 0; kb < 4; ++kb)
            afr[kb] = *(const short8b*)&Et[wv * 16 + li][kb * 32 + lg * 8];

        #pragma unroll
        for (int h = 0; h < HEADS; ++h) {
            f32x4 acc = {0.f, 0.f, 0.f, 0.f};
            #pragma unroll
            for (int kb = 0; kb < 4; ++kb) {
                short8b bfr = *(const short8b*)&WeT[h * 16 + li][kb * 32 + lg * 8];
                acc = __builtin_amdgcn_mfma_f32_16x16x32_bf16(afr[kb], bfr, acc, 0, 0, 0);
            }
            float p[4];
            #pragma unroll
            for (int j = 0; j < 4; ++j) {
                float x = acc[j] + be_h[h] + bf2f(g_hs[j][h]) + bf2f(g_hr[j][h]);
                x = x > 0.f ? x : 0.01f * x;
                p[j] = x * a_h[h];
            }
            #pragma unroll
            for (int j = 0; j < 4; ++j) {
                p[j] += __shfl_xor(p[j], 1);
                p[j] += __shfl_xor(p[j], 2);
            }
            float q = (jm & 1) ? ((jm & 2) ? p[3] : p[1])
                               : ((jm & 2) ? p[2] : p[0]);
            q += __shfl_xor(q, 4);
            q += __shfl_xor(q, 8);
            float e_ = __expf(q);
            if (li < 4) {
                int pos = pbase + lg * 4 + li;
                ex[(size_t)pos * HEADS + h] = e_;    // CSR-contiguous write
            }
        }
        __builtin_amdgcn_wave_barrier();
    }
}

// ---------- K3: per-node gather; csr4/ex contiguous, hs random --------------
__global__ __launch_bounds__(256) void k_gather_out(
    const int* __restrict__ rowptr, const int4* __restrict__ csr4,
    const unsigned short* __restrict__ hsb, const float* __restrict__ ex,
    float* __restrict__ out)
{
    int r = blockIdx.x * 4 + (threadIdx.x >> 6);
    int l = threadIdx.x & 63;
    int h = l >> 3;
    int beg = rowptr[r], end = rowptr[r + 1];

    float2 acc = make_float2(0.f, 0.f);
    float dsum = 0.f;
    for (int j0 = beg; j0 < end; j0 += 16) {
        int cnt = end - j0;
        int s[16]; float w[16];
        #pragma unroll
        for (int q = 0; q < 16; ++q)
            if (q < cnt) { s[q] = csr4[j0 + q].y; w[q] = ex[(size_t)(j0 + q) * HEADS + h]; }
        #pragma unroll
        for (int q = 0; q < 16; ++q)
            if (q < cnt) {
                ushort2 hv = *(const ushort2*)&hsb[(size_t)s[q] * D + 2 * l];
                acc.x += w[q] * bf2f(hv.x);
                acc.y += w[q] * bf2f(hv.y);
                dsum  += w[q];
            }
    }
    float inv = (end > beg && dsum != 0.f) ? (1.0f / dsum) : 0.f;
    acc.x *= inv; acc.y *= inv;
    *(float2*)&out[(size_t)r * D + 2 * l] = acc;
}

extern "C" void kernel_launch(void* const* d_in, const int* in_sizes, int n_in,
                              void* d_out, int out_size, void* d_ws, size_t ws_size,
                              hipStream_t stream) {
    const float* nodes     = (const float*)d_in[0];
    const float* edges     = (const float*)d_in[1];
    const int*   senders   = (const int*)d_in[2];
    const int*   receivers = (const int*)d_in[3];
    const float* Ws = (const float*)d_in[4];
    const float* bs = (const float*)d_in[5];
    const float* Wr = (const float*)d_in[6];
    const float* br = (const float*)d_in[7];
    const float* We = (const float*)d_in[8];
    const float* be = (const float*)d_in[9];
    const float* a  = (const float*)d_in[10];
    float* out = (float*)d_out;

    unsigned short* hsb = (unsigned short*)d_ws;          // 6.4M bf16
    unsigned short* hrb = hsb + (size_t)N_NODES * D;      // 6.4M bf16
    float* ex   = (float*)(hrb + (size_t)N_NODES * D);    // 6.4M f32 (CSR order)
    int* deg    = (int*)(ex + (size_t)N_EDGES * HEADS);   // 50000
    int* rowptr = deg + N_NODES;                          // 50001
    int* cursor = rowptr + N_NODES + 1;                   // 50000
    // align csr4 to 16B
    size_t off = (size_t)(cursor + N_NODES - (int*)d_ws);
    off = (off + 3) & ~(size_t)3;
    int4* csr4 = (int4*)((int*)d_ws + off);               // 800000 x 16B

    (void)hipMemsetAsync(deg, 0, N_NODES * sizeof(int), stream);
    k_hist<<<N_EDGES / 256, 256, 0, stream>>>(receivers, deg);
    k_scan<<<1, 1024, 0, stream>>>(deg, rowptr, cursor);
    k_fill<<<N_EDGES / 256, 256, 0, stream>>>(receivers, senders, cursor, csr4);
    int ntiles_n = (N_NODES + K1_ROWS - 1) / K1_ROWS;
    k_node_proj_mfma<<<ntiles_n * 2, 256, 0, stream>>>(nodes, Ws, bs, Wr, br, hsb, hrb);
    k_edge_logits_mfma<<<512, 512, 0, stream>>>(edges, csr4, We, be, a,
                                                hsb, hrb, ex);
    k_gather_out<<<N_NODES / 4, 256, 0, stream>>>(rowptr, csr4, hsb, ex, out);
}

// Round 15
// 460.695 us; speedup vs baseline: 1.5025x; 1.0963x over previous
//
#include <hip/hip_runtime.h>

#define N_NODES 50000
#define N_EDGES 800000
#define D 128
#define HEADS 8

typedef __attribute__((ext_vector_type(8))) short short8b;  // 8 bf16 (4 VGPRs)
typedef __attribute__((ext_vector_type(4))) float f32x4;

__device__ __forceinline__ unsigned short f2bf_rne(float f) {
    unsigned int u = __float_as_uint(f);
    u += 0x7FFFu + ((u >> 16) & 1u);   // round-to-nearest-even
    return (unsigned short)(u >> 16);
}
__device__ __forceinline__ float bf2f(unsigned short u) {
    return __uint_as_float(((unsigned int)u) << 16);
}

// ---------------- K1 (MFMA): hs/hr = bf16(nodes @ W + b) --------------------
#define K1_ROWS 128
__global__ __launch_bounds__(256, 3) void k_node_proj_mfma(
    const float* __restrict__ nodes,
    const float* __restrict__ Ws, const float* __restrict__ bs,
    const float* __restrict__ Wr, const float* __restrict__ br,
    unsigned short* __restrict__ hsb, unsigned short* __restrict__ hrb)
{
    __shared__ __align__(16) unsigned short WT[D][136];   // [col][k] 34816 B
    __shared__ __align__(16) unsigned short At[64][136];  // [row][k] 17408 B
    const int ntiles = (N_NODES + K1_ROWS - 1) / K1_ROWS;   // 391
    int bx = blockIdx.x;
    int proj = (bx >= ntiles) ? 1 : 0;
    int tile = proj ? (bx - ntiles) : bx;
    const float* W    = proj ? Wr : Ws;
    const float* bias = proj ? br : bs;
    unsigned short* outp = proj ? hrb : hsb;
    int t = threadIdx.x;
    int lane = t & 63;
    int wv = t >> 6;
    int lg = lane >> 4;
    int li = lane & 15;

    #pragma unroll 8
    for (int j = 0; j < 64; ++j) {
        int idx = t + 256 * j;     // k*128+c
        int k = idx >> 7, c = idx & 127;
        WT[c][k] = f2bf_rne(W[idx]);
    }
    float b_ct[8];
    #pragma unroll
    for (int ct = 0; ct < 8; ++ct) b_ct[ct] = bias[ct * 16 + li];

    #pragma unroll 1
    for (int sub = 0; sub < 2; ++sub) {
        int row0 = tile * K1_ROWS + sub * 64;
        if (row0 >= N_NODES) break;          // uniform
        __syncthreads();
        {   // stage 64 node rows -> bf16 LDS
            const float4* Nv = (const float4*)nodes;
            #pragma unroll
            for (int j = 0; j < 8; ++j) {
                int fi = t + 256 * j;
                int r = row0 + (fi >> 5);
                float4 v = make_float4(0.f, 0.f, 0.f, 0.f);
                if (r < N_NODES) v = Nv[(size_t)r * 32 + (fi & 31)];
                ushort4 b;
                b.x = f2bf_rne(v.x); b.y = f2bf_rne(v.y);
                b.z = f2bf_rne(v.z); b.w = f2bf_rne(v.w);
                *(ushort4*)&At[fi >> 5][(fi & 31) * 4] = b;
            }
        }
        __syncthreads();

        short8b afr[4];
        #pragma unroll
        for (int kb = 0; kb < 4; ++kb)
            afr[kb] = *(const short8b*)&At[wv * 16 + li][kb * 32 + lg * 8];

        #pragma unroll
        for (int ct = 0; ct < 8; ++ct) {
            f32x4 acc = {0.f, 0.f, 0.f, 0.f};
            #pragma unroll
            for (int kb = 0; kb < 4; ++kb) {
                short8b bfr = *(const short8b*)&WT[ct * 16 + li][kb * 32 + lg * 8];
                acc = __builtin_amdgcn_mfma_f32_16x16x32_bf16(afr[kb], bfr, acc, 0, 0, 0);
            }
            #pragma unroll
            for (int j = 0; j < 4; ++j) {
                int r = row0 + wv * 16 + lg * 4 + j;
                if (r < N_NODES)
                    outp[(size_t)r * D + ct * 16 + li] = f2bf_rne(acc[j] + b_ct[ct]);
            }
        }
    }
}

// ------------------------- CSR build (runs before K2) ------------------------
__global__ __launch_bounds__(256) void k_hist(
    const int* __restrict__ receivers, int* __restrict__ deg)
{
    int i = blockIdx.x * 256 + threadIdx.x;
    if (i < N_EDGES) atomicAdd(&deg[receivers[i]], 1);
}

#define SCAN_CHUNK 49
__global__ __launch_bounds__(1024) void k_scan(
    const int* __restrict__ deg, int* __restrict__ rowptr, int* __restrict__ cursor)
{
    __shared__ int sm[1024];
    int t = threadIdx.x;
    int base = t * SCAN_CHUNK;
    int lsum = 0;
    #pragma unroll 4
    for (int i = 0; i < SCAN_CHUNK; ++i) {
        int idx = base + i;
        if (idx < N_NODES) lsum += deg[idx];
    }
    sm[t] = lsum;
    __syncthreads();
    for (int off = 1; off < 1024; off <<= 1) {
        int v = (t >= off) ? sm[t - off] : 0;
        __syncthreads();
        sm[t] += v;
        __syncthreads();
    }
    int run = (t > 0) ? sm[t - 1] : 0;
    for (int i = 0; i < SCAN_CHUNK; ++i) {
        int idx = base + i;
        if (idx < N_NODES) {
            rowptr[idx] = run;
            cursor[idx] = run;
            run += deg[idx];
        }
    }
    if (t == 1023) rowptr[N_NODES] = sm[1023];
}

__global__ __launch_bounds__(256) void k_fill(
    const int* __restrict__ receivers, const int* __restrict__ senders,
    int* __restrict__ cursor,
    int* __restrict__ eids, int* __restrict__ s_csr, int* __restrict__ r_csr)
{
    int i = blockIdx.x * 256 + threadIdx.x;
    if (i < N_EDGES) {
        int r = receivers[i];
        int pos = atomicAdd(&cursor[r], 1);
        eids[pos]  = i;
        s_csr[pos] = senders[i];
        r_csr[pos] = r;
    }
}

// ------- K2 (MFMA bf16, CSR order, wave-local staging, barrier-free) ---------
#define BLK_E 64
__global__ __launch_bounds__(256, 3) void k_edge_logits_mfma(
    const float* __restrict__ edges,
    const int* __restrict__ eids, const int* __restrict__ s_csr,
    const int* __restrict__ r_csr,
    const float* __restrict__ We, const float* __restrict__ be,
    const float* __restrict__ a,
    const unsigned short* __restrict__ hsb, const unsigned short* __restrict__ hrb,
    float* __restrict__ ex)
{
    __shared__ __align__(16) unsigned short WeT[D][136];    // [col][k] 34816 B
    __shared__ __align__(16) unsigned short Et[BLK_E][136]; // [edge][k] 17408 B
    int t = threadIdx.x;
    int lane = t & 63;
    int wv = t >> 6;
    int lg = lane >> 4;
    int li = lane & 15;

    #pragma unroll 8
    for (int j = 0; j < 64; ++j) {
        int idx = t + 256 * j;
        int k = idx >> 7, c = idx & 127;
        WeT[c][k] = f2bf_rne(We[idx]);
    }
    float a_h[HEADS], be_h[HEADS];
    #pragma unroll
    for (int h = 0; h < HEADS; ++h) {
        a_h[h]  = a[h * 16 + li];
        be_h[h] = be[h * 16 + li];
    }
    int jm = li & 3;
    __syncthreads();   // WeT ready; the ONLY block barrier

    const int ntiles = N_EDGES / BLK_E;   // 12500
    for (int tile = blockIdx.x; tile < ntiles; tile += gridDim.x) {
        int pbase = tile * BLK_E + wv * 16;   // this wave's 16 CSR rows

        // stage this wave's 16 edge rows -> bf16 LDS (coalesced 512B rows)
        {
            const float4* Ev = (const float4*)edges;
            #pragma unroll
            for (int j = 0; j < 8; ++j) {
                int fi = lane + 64 * j;        // 0..511
                int rloc = fi >> 5;            // 0..15
                int e = eids[pbase + rloc];    // broadcast
                float4 v = Ev[(size_t)e * 32 + (fi & 31)];
                ushort4 b;
                b.x = f2bf_rne(v.x); b.y = f2bf_rne(v.y);
                b.z = f2bf_rne(v.z); b.w = f2bf_rne(v.w);
                *(ushort4*)&Et[wv * 16 + rloc][(fi & 31) * 4] = b;
            }
        }

        // independent vmem while LDS writes drain
        int sj[4], rj[4];
        #pragma unroll
        for (int j = 0; j < 4; ++j) {
            sj[j] = s_csr[pbase + lg * 4 + j];
            rj[j] = r_csr[pbase + lg * 4 + j];
        }
        unsigned short g_hs[4][HEADS], g_hr[4][HEADS];
        #pragma unroll
        for (int j = 0; j < 4; ++j) {
            const unsigned short* hsrow = hsb + (size_t)sj[j] * D + li;
            const unsigned short* hrrow = hrb + (size_t)rj[j] * D + li;
            #pragma unroll
            for (int h = 0; h < HEADS; ++h) {
                g_hs[j][h] = hsrow[h * 16];
                g_hr[j][h] = hrrow[h * 16];
            }
        }

        // intra-wave LDS write->read fence (no block barrier needed)
        asm volatile("s_waitcnt lgkmcnt(0)" ::: "memory");
        __builtin_amdgcn_sched_barrier(0);

        short8b afr[4];
        #pragma unroll
        for (int kb = 0; kb < 4; ++kb)
            afr[kb] = *(const short8b*)&Et[wv * 16 + li][kb * 32 + lg * 8];

        #pragma unroll
        for (int h = 0; h < HEADS; ++h) {
            f32x4 acc = {0.f, 0.f, 0.f, 0.f};
            #pragma unroll
            for (int kb = 0; kb < 4; ++kb) {
                short8b bfr = *(const short8b*)&WeT[h * 16 + li][kb * 32 + lg * 8];
                acc = __builtin_amdgcn_mfma_f32_16x16x32_bf16(afr[kb], bfr, acc, 0, 0, 0);
            }
            float p[4];
            #pragma unroll
            for (int j = 0; j < 4; ++j) {
                float x = acc[j] + be_h[h] + bf2f(g_hs[j][h]) + bf2f(g_hr[j][h]);
                x = x > 0.f ? x : 0.01f * x;
                p[j] = x * a_h[h];
            }
            #pragma unroll
            for (int j = 0; j < 4; ++j) {
                p[j] += __shfl_xor(p[j], 1);
                p[j] += __shfl_xor(p[j], 2);
            }
            float q = (jm & 1) ? ((jm & 2) ? p[3] : p[1])
                               : ((jm & 2) ? p[2] : p[0]);
            q += __shfl_xor(q, 4);
            q += __shfl_xor(q, 8);
            float e_ = __expf(q);
            if (li < 4) {
                int pos = pbase + lg * 4 + li;
                ex[(size_t)pos * HEADS + h] = e_;    // CSR-contiguous write
            }
        }
        __builtin_amdgcn_wave_barrier();
    }
}

// ---------- K3: per-node gather; s_csr/ex contiguous, hs random -------------
__global__ __launch_bounds__(256) void k_gather_out(
    const int* __restrict__ rowptr, const int* __restrict__ s_csr,
    const unsigned short* __restrict__ hsb, const float* __restrict__ ex,
    float* __restrict__ out)
{
    int r = blockIdx.x * 4 + (threadIdx.x >> 6);
    int l = threadIdx.x & 63;
    int h = l >> 3;
    int beg = rowptr[r], end = rowptr[r + 1];

    float2 acc = make_float2(0.f, 0.f);
    float dsum = 0.f;
    for (int j0 = beg; j0 < end; j0 += 16) {
        int cnt = end - j0;
        int s[16]; float w[16];
        #pragma unroll
        for (int q = 0; q < 16; ++q)
            if (q < cnt) { s[q] = s_csr[j0 + q]; w[q] = ex[(size_t)(j0 + q) * HEADS + h]; }
        #pragma unroll
        for (int q = 0; q < 16; ++q)
            if (q < cnt) {
                ushort2 hv = *(const ushort2*)&hsb[(size_t)s[q] * D + 2 * l];
                acc.x += w[q] * bf2f(hv.x);
                acc.y += w[q] * bf2f(hv.y);
                dsum  += w[q];
            }
    }
    float inv = (end > beg && dsum != 0.f) ? (1.0f / dsum) : 0.f;
    acc.x *= inv; acc.y *= inv;
    *(float2*)&out[(size_t)r * D + 2 * l] = acc;
}

extern "C" void kernel_launch(void* const* d_in, const int* in_sizes, int n_in,
                              void* d_out, int out_size, void* d_ws, size_t ws_size,
                              hipStream_t stream) {
    const float* nodes     = (const float*)d_in[0];
    const float* edges     = (const float*)d_in[1];
    const int*   senders   = (const int*)d_in[2];
    const int*   receivers = (const int*)d_in[3];
    const float* Ws = (const float*)d_in[4];
    const float* bs = (const float*)d_in[5];
    const float* Wr = (const float*)d_in[6];
    const float* br = (const float*)d_in[7];
    const float* We = (const float*)d_in[8];
    const float* be = (const float*)d_in[9];
    const float* a  = (const float*)d_in[10];
    float* out = (float*)d_out;

    unsigned short* hsb = (unsigned short*)d_ws;          // 6.4M bf16
    unsigned short* hrb = hsb + (size_t)N_NODES * D;      // 6.4M bf16
    float* ex   = (float*)(hrb + (size_t)N_NODES * D);    // 6.4M f32 (CSR order)
    int* deg    = (int*)(ex + (size_t)N_EDGES * HEADS);   // 50000
    int* rowptr = deg + N_NODES;                          // 50001
    int* cursor = rowptr + N_NODES + 1;                   // 50000
    int* eids   = cursor + N_NODES;                       // 800000
    int* s_csr  = eids + N_EDGES;                         // 800000
    int* r_csr  = s_csr + N_EDGES;                        // 800000

    (void)hipMemsetAsync(deg, 0, N_NODES * sizeof(int), stream);
    k_hist<<<N_EDGES / 256, 256, 0, stream>>>(receivers, deg);
    k_scan<<<1, 1024, 0, stream>>>(deg, rowptr, cursor);
    k_fill<<<N_EDGES / 256, 256, 0, stream>>>(receivers, senders, cursor,
                                              eids, s_csr, r_csr);
    int ntiles_n = (N_NODES + K1_ROWS - 1) / K1_ROWS;
    k_node_proj_mfma<<<ntiles_n * 2, 256, 0, stream>>>(nodes, Ws, bs, Wr, br, hsb, hrb);
    k_edge_logits_mfma<<<2500, 256, 0, stream>>>(edges, eids, s_csr, r_csr,
                                                 We, be, a, hsb, hrb, ex);
    k_gather_out<<<N_NODES / 4, 256, 0, stream>>>(rowptr, s_csr, hsb, ex, out);
}

// Round 16
// 444.143 us; speedup vs baseline: 1.5585x; 1.0373x over previous
//
#include <hip/hip_runtime.h>

#define N_NODES 50000
#define N_EDGES 800000
#define D 128
#define HEADS 8

typedef __attribute__((ext_vector_type(8))) short short8b;  // 8 bf16 (4 VGPRs)
typedef __attribute__((ext_vector_type(4))) float f32x4;

__device__ __forceinline__ unsigned short f2bf_rne(float f) {
    unsigned int u = __float_as_uint(f);
    u += 0x7FFFu + ((u >> 16) & 1u);   // round-to-nearest-even
    return (unsigned short)(u >> 16);
}
__device__ __forceinline__ float bf2f(unsigned short u) {
    return __uint_as_float(((unsigned int)u) << 16);
}

// DPP 16-lane row sum (4 VALU ops, no DS traffic); ctrl must be constexpr
template <int CTRL>
__device__ __forceinline__ float dpp_radd(float v) {
    int s = __builtin_amdgcn_update_dpp(0, __float_as_int(v), CTRL, 0xF, 0xF, true);
    return v + __int_as_float(s);
}
__device__ __forceinline__ float rowsum16(float v) {
    v = dpp_radd<0xB1>(v);    // quad_perm xor1
    v = dpp_radd<0x4E>(v);    // quad_perm xor2
    v = dpp_radd<0x141>(v);   // row_half_mirror
    v = dpp_radd<0x140>(v);   // row_mirror
    return v;                 // all 16 lanes hold the row sum
}

// ---------------- K1 (MFMA): hs/hr = bf16(nodes @ W + b) --------------------
#define K1_ROWS 128
__global__ __launch_bounds__(256, 3) void k_node_proj_mfma(
    const float* __restrict__ nodes,
    const float* __restrict__ Ws, const float* __restrict__ bs,
    const float* __restrict__ Wr, const float* __restrict__ br,
    unsigned short* __restrict__ hsb, unsigned short* __restrict__ hrb)
{
    __shared__ __align__(16) unsigned short WT[D][136];   // [col][k] 34816 B
    __shared__ __align__(16) unsigned short At[64][136];  // [row][k] 17408 B
    const int ntiles = (N_NODES + K1_ROWS - 1) / K1_ROWS;   // 391
    int bx = blockIdx.x;
    int proj = (bx >= ntiles) ? 1 : 0;
    int tile = proj ? (bx - ntiles) : bx;
    const float* W    = proj ? Wr : Ws;
    const float* bias = proj ? br : bs;
    unsigned short* outp = proj ? hrb : hsb;
    int t = threadIdx.x;
    int lane = t & 63;
    int wv = t >> 6;
    int lg = lane >> 4;
    int li = lane & 15;

    #pragma unroll 8
    for (int j = 0; j < 64; ++j) {
        int idx = t + 256 * j;     // k*128+c
        int k = idx >> 7, c = idx & 127;
        WT[c][k] = f2bf_rne(W[idx]);
    }
    float b_ct[8];
    #pragma unroll
    for (int ct = 0; ct < 8; ++ct) b_ct[ct] = bias[ct * 16 + li];

    #pragma unroll 1
    for (int sub = 0; sub < 2; ++sub) {
        int row0 = tile * K1_ROWS + sub * 64;
        if (row0 >= N_NODES) break;          // uniform
        __syncthreads();
        {   // stage 64 node rows -> bf16 LDS
            const float4* Nv = (const float4*)nodes;
            #pragma unroll
            for (int j = 0; j < 8; ++j) {
                int fi = t + 256 * j;
                int r = row0 + (fi >> 5);
                float4 v = make_float4(0.f, 0.f, 0.f, 0.f);
                if (r < N_NODES) v = Nv[(size_t)r * 32 + (fi & 31)];
                ushort4 b;
                b.x = f2bf_rne(v.x); b.y = f2bf_rne(v.y);
                b.z = f2bf_rne(v.z); b.w = f2bf_rne(v.w);
                *(ushort4*)&At[fi >> 5][(fi & 31) * 4] = b;
            }
        }
        __syncthreads();

        short8b afr[4];
        #pragma unroll
        for (int kb = 0; kb < 4; ++kb)
            afr[kb] = *(const short8b*)&At[wv * 16 + li][kb * 32 + lg * 8];

        #pragma unroll
        for (int ct = 0; ct < 8; ++ct) {
            f32x4 acc = {0.f, 0.f, 0.f, 0.f};
            #pragma unroll
            for (int kb = 0; kb < 4; ++kb) {
                short8b bfr = *(const short8b*)&WT[ct * 16 + li][kb * 32 + lg * 8];
                acc = __builtin_amdgcn_mfma_f32_16x16x32_bf16(afr[kb], bfr, acc, 0, 0, 0);
            }
            #pragma unroll
            for (int j = 0; j < 4; ++j) {
                int r = row0 + wv * 16 + lg * 4 + j;
                if (r < N_NODES)
                    outp[(size_t)r * D + ct * 16 + li] = f2bf_rne(acc[j] + b_ct[ct]);
            }
        }
    }
}

// ------------------------- CSR build (runs before K2) ------------------------
__global__ __launch_bounds__(256) void k_hist(
    const int* __restrict__ receivers, int* __restrict__ deg)
{
    int i = blockIdx.x * 256 + threadIdx.x;
    if (i < N_EDGES) atomicAdd(&deg[receivers[i]], 1);
}

#define SCAN_CHUNK 49
__global__ __launch_bounds__(1024) void k_scan(
    const int* __restrict__ deg, int* __restrict__ rowptr, int* __restrict__ cursor)
{
    __shared__ int sm[1024];
    int t = threadIdx.x;
    int base = t * SCAN_CHUNK;
    int lsum = 0;
    #pragma unroll 4
    for (int i = 0; i < SCAN_CHUNK; ++i) {
        int idx = base + i;
        if (idx < N_NODES) lsum += deg[idx];
    }
    sm[t] = lsum;
    __syncthreads();
    for (int off = 1; off < 1024; off <<= 1) {
        int v = (t >= off) ? sm[t - off] : 0;
        __syncthreads();
        sm[t] += v;
        __syncthreads();
    }
    int run = (t > 0) ? sm[t - 1] : 0;
    for (int i = 0; i < SCAN_CHUNK; ++i) {
        int idx = base + i;
        if (idx < N_NODES) {
            rowptr[idx] = run;
            cursor[idx] = run;
            run += deg[idx];
        }
    }
    if (t == 1023) rowptr[N_NODES] = sm[1023];
}

// s_csr[pos] = sender (scattered); pos_csr[i] = pos (coalesced)
__global__ __launch_bounds__(256) void k_fill(
    const int* __restrict__ receivers, const int* __restrict__ senders,
    int* __restrict__ cursor,
    int* __restrict__ s_csr, int* __restrict__ pos_csr)
{
    int i = blockIdx.x * 256 + threadIdx.x;
    if (i < N_EDGES) {
        int r = receivers[i];
        int pos = atomicAdd(&cursor[r], 1);
        s_csr[pos]  = senders[i];
        pos_csr[i]  = pos;
    }
}

// ------- K2 (MFMA bf16, SEQUENTIAL edge order, scatter ex to CSR pos) --------
// Edge rows stream sequentially (full-BW 1KB/instr staging); senders/receivers/
// pos_csr are streams; only hs/hr are gathers. Epilogue: DPP rowsum + lane
// repack -> one scattered float2 store per lane (round-11-verified mapping).
#define BLK_E 64
__global__ __launch_bounds__(256, 3) void k_edge_logits_mfma(
    const float* __restrict__ edges,
    const int* __restrict__ senders, const int* __restrict__ receivers,
    const int* __restrict__ pos_csr,
    const float* __restrict__ We, const float* __restrict__ be,
    const float* __restrict__ a,
    const unsigned short* __restrict__ hsb, const unsigned short* __restrict__ hrb,
    float* __restrict__ ex)
{
    __shared__ __align__(16) unsigned short WeT[D][136];    // [col][k] 34816 B
    __shared__ __align__(16) unsigned short Et[BLK_E][136]; // [edge][k] 17408 B
    int t = threadIdx.x;
    int lane = t & 63;
    int wv = t >> 6;
    int lg = lane >> 4;
    int li = lane & 15;

    #pragma unroll 8
    for (int j = 0; j < 64; ++j) {
        int idx = t + 256 * j;
        int k = idx >> 7, c = idx & 127;
        WeT[c][k] = f2bf_rne(We[idx]);
    }
    float a_h[HEADS], be_h[HEADS];
    #pragma unroll
    for (int h = 0; h < HEADS; ++h) {
        a_h[h]  = a[h * 16 + li];
        be_h[h] = be[h * 16 + li];
    }
    __syncthreads();   // WeT ready; the ONLY block barrier

    const int ntiles = N_EDGES / BLK_E;   // 12500
    const float4* Ev = (const float4*)edges;

    for (int tile = blockIdx.x; tile < ntiles; tile += gridDim.x) {
        int pb = tile * BLK_E + wv * 16;   // this wave's 16 sequential edges

        // stage 16 sequential edge rows -> bf16 LDS (1KB/instr, streaming)
        #pragma unroll
        for (int j = 0; j < 8; ++j) {
            int fi = lane + 64 * j;        // 0..511
            int rloc = fi >> 5;            // 0..15
            float4 v = Ev[(size_t)(pb + rloc) * 32 + (fi & 31)];
            ushort4 b;
            b.x = f2bf_rne(v.x); b.y = f2bf_rne(v.y);
            b.z = f2bf_rne(v.z); b.w = f2bf_rne(v.w);
            *(ushort4*)&Et[wv * 16 + rloc][(fi & 31) * 4] = b;
        }

        // streams: indices + this lane's CSR position (edge o = 4*lg+(li>>2))
        int sj[4], rj[4];
        #pragma unroll
        for (int j = 0; j < 4; ++j) {
            sj[j] = senders[pb + lg * 4 + j];
            rj[j] = receivers[pb + lg * 4 + j];
        }
        int o = 4 * lg + (li >> 2);
        int mypos = pos_csr[pb + o];

        // gathers (random 16B-class, L2/L3-resident)
        unsigned short g_hs[4][HEADS], g_hr[4][HEADS];
        #pragma unroll
        for (int j = 0; j < 4; ++j) {
            const unsigned short* hsrow = hsb + (size_t)sj[j] * D + li;
            const unsigned short* hrrow = hrb + (size_t)rj[j] * D + li;
            #pragma unroll
            for (int h = 0; h < HEADS; ++h) {
                g_hs[j][h] = hsrow[h * 16];
                g_hr[j][h] = hrrow[h * 16];
            }
        }

        // intra-wave LDS write->read fence (no block barrier needed)
        asm volatile("s_waitcnt lgkmcnt(0)" ::: "memory");
        __builtin_amdgcn_sched_barrier(0);

        short8b afr[4];
        #pragma unroll
        for (int kb = 0; kb < 4; ++kb)
            afr[kb] = *(const short8b*)&Et[wv * 16 + li][kb * 32 + lg * 8];

        float hold[8];   // exp(logit) per head for this lane's edge o
        #pragma unroll
        for (int h = 0; h < HEADS; ++h) {
            f32x4 acc = {0.f, 0.f, 0.f, 0.f};
            #pragma unroll
            for (int kb = 0; kb < 4; ++kb) {
                short8b bfr = *(const short8b*)&WeT[h * 16 + li][kb * 32 + lg * 8];
                acc = __builtin_amdgcn_mfma_f32_16x16x32_bf16(afr[kb], bfr, acc, 0, 0, 0);
            }
            float pr[4];
            #pragma unroll
            for (int j = 0; j < 4; ++j) {
                float x = acc[j] + be_h[h] + bf2f(g_hs[j][h]) + bf2f(g_hr[j][h]);
                x = fmaxf(x, 0.01f * x);            // leaky relu
                pr[j] = rowsum16(x * a_h[h]);       // 4 DPP adds, no DS ops
            }
            float qa = (li & 4) ? pr[1] : pr[0];
            float qb = (li & 4) ? pr[3] : pr[2];
            hold[h] = __expf((li & 8) ? qb : qa);   // edge o = 4lg+(li>>2)
        }
        // lane packs heads {h1, h1+1} of its edge -> one scattered 8B store
        {
            float a0 = (li & 1) ? hold[2] : hold[0];
            float a1 = (li & 1) ? hold[6] : hold[4];
            float ea = (li & 2) ? a1 : a0;          // hold[h1]
            float b0 = (li & 1) ? hold[3] : hold[1];
            float b1 = (li & 1) ? hold[7] : hold[5];
            float eb = (li & 2) ? b1 : b0;          // hold[h1+1]
            int h1 = 2 * (li & 3);
            *(float2*)&ex[(size_t)mypos * HEADS + h1] = make_float2(ea, eb);
        }
        __builtin_amdgcn_wave_barrier();
    }
}

// ---------- K3: per-node gather; s_csr/ex contiguous, hs random -------------
__global__ __launch_bounds__(256) void k_gather_out(
    const int* __restrict__ rowptr, const int* __restrict__ s_csr,
    const unsigned short* __restrict__ hsb, const float* __restrict__ ex,
    float* __restrict__ out)
{
    int r = blockIdx.x * 4 + (threadIdx.x >> 6);
    int l = threadIdx.x & 63;
    int h = l >> 3;
    int beg = rowptr[r], end = rowptr[r + 1];

    float2 acc = make_float2(0.f, 0.f);
    float dsum = 0.f;
    for (int j0 = beg; j0 < end; j0 += 16) {
        int cnt = end - j0;
        int s[16]; float w[16];
        #pragma unroll
        for (int q = 0; q < 16; ++q)
            if (q < cnt) { s[q] = s_csr[j0 + q]; w[q] = ex[(size_t)(j0 + q) * HEADS + h]; }
        #pragma unroll
        for (int q = 0; q < 16; ++q)
            if (q < cnt) {
                ushort2 hv = *(const ushort2*)&hsb[(size_t)s[q] * D + 2 * l];
                acc.x += w[q] * bf2f(hv.x);
                acc.y += w[q] * bf2f(hv.y);
                dsum  += w[q];
            }
    }
    float inv = (end > beg && dsum != 0.f) ? (1.0f / dsum) : 0.f;
    acc.x *= inv; acc.y *= inv;
    *(float2*)&out[(size_t)r * D + 2 * l] = acc;
}

extern "C" void kernel_launch(void* const* d_in, const int* in_sizes, int n_in,
                              void* d_out, int out_size, void* d_ws, size_t ws_size,
                              hipStream_t stream) {
    const float* nodes     = (const float*)d_in[0];
    const float* edges     = (const float*)d_in[1];
    const int*   senders   = (const int*)d_in[2];
    const int*   receivers = (const int*)d_in[3];
    const float* Ws = (const float*)d_in[4];
    const float* bs = (const float*)d_in[5];
    const float* Wr = (const float*)d_in[6];
    const float* br = (const float*)d_in[7];
    const float* We = (const float*)d_in[8];
    const float* be = (const float*)d_in[9];
    const float* a  = (const float*)d_in[10];
    float* out = (float*)d_out;

    unsigned short* hsb = (unsigned short*)d_ws;          // 6.4M bf16
    unsigned short* hrb = hsb + (size_t)N_NODES * D;      // 6.4M bf16
    float* ex    = (float*)(hrb + (size_t)N_NODES * D);   // 6.4M f32 (CSR order)
    int* deg     = (int*)(ex + (size_t)N_EDGES * HEADS);  // 50000
    int* rowptr  = deg + N_NODES;                         // 50001
    int* cursor  = rowptr + N_NODES + 1;                  // 50000
    int* s_csr   = cursor + N_NODES;                      // 800000
    int* pos_csr = s_csr + N_EDGES;                       // 800000

    (void)hipMemsetAsync(deg, 0, N_NODES * sizeof(int), stream);
    k_hist<<<N_EDGES / 256, 256, 0, stream>>>(receivers, deg);
    k_scan<<<1, 1024, 0, stream>>>(deg, rowptr, cursor);
    k_fill<<<N_EDGES / 256, 256, 0, stream>>>(receivers, senders, cursor,
                                              s_csr, pos_csr);
    int ntiles_n = (N_NODES + K1_ROWS - 1) / K1_ROWS;
    k_node_proj_mfma<<<ntiles_n * 2, 256, 0, stream>>>(nodes, Ws, bs, Wr, br, hsb, hrb);
    k_edge_logits_mfma<<<2500, 256, 0, stream>>>(edges, senders, receivers, pos_csr,
                                                 We, be, a, hsb, hrb, ex);
    k_gather_out<<<N_NODES / 4, 256, 0, stream>>>(rowptr, s_csr, hsb, ex, out);
}

// Round 17
// 404.402 us; speedup vs baseline: 1.7116x; 1.0983x over previous
//
#include <hip/hip_runtime.h>

#define N_NODES 50000
#define N_EDGES 800000
#define D 128
#define HEADS 8

typedef __attribute__((ext_vector_type(8))) short short8b;  // 8 bf16 (4 VGPRs)
typedef __attribute__((ext_vector_type(4))) float f32x4;

__device__ __forceinline__ unsigned short f2bf_rne(float f) {
    unsigned int u = __float_as_uint(f);
    u += 0x7FFFu + ((u >> 16) & 1u);   // round-to-nearest-even
    return (unsigned short)(u >> 16);
}
__device__ __forceinline__ float bf2f(unsigned short u) {
    return __uint_as_float(((unsigned int)u) << 16);
}

// DPP 16-lane row sum (4 VALU ops, no DS traffic); ctrl must be constexpr
template <int CTRL>
__device__ __forceinline__ float dpp_radd(float v) {
    int s = __builtin_amdgcn_update_dpp(0, __float_as_int(v), CTRL, 0xF, 0xF, true);
    return v + __int_as_float(s);
}
__device__ __forceinline__ float rowsum16(float v) {
    v = dpp_radd<0xB1>(v);    // quad_perm xor1
    v = dpp_radd<0x4E>(v);    // quad_perm xor2
    v = dpp_radd<0x141>(v);   // row_half_mirror
    v = dpp_radd<0x140>(v);   // row_mirror
    return v;                 // all 16 lanes hold the row sum
}

// ---------------- shared projection body: out = bf16(nodes @ W + b) ---------
#define K1_ROWS 128
#define K1_TILES ((N_NODES + K1_ROWS - 1) / K1_ROWS)   // 391

__device__ __forceinline__ void proj_body(
    int tile, const float* __restrict__ nodes,
    const float* __restrict__ W, const float* __restrict__ bias,
    unsigned short* __restrict__ outp)
{
    __shared__ __align__(16) unsigned short WT[D][136];   // [col][k] 34816 B
    __shared__ __align__(16) unsigned short At[64][136];  // [row][k] 17408 B
    int t = threadIdx.x;
    int lane = t & 63;
    int wv = t >> 6;
    int lg = lane >> 4;
    int li = lane & 15;

    #pragma unroll 8
    for (int j = 0; j < 64; ++j) {
        int idx = t + 256 * j;     // k*128+c
        int k = idx >> 7, c = idx & 127;
        WT[c][k] = f2bf_rne(W[idx]);
    }
    float b_ct[8];
    #pragma unroll
    for (int ct = 0; ct < 8; ++ct) b_ct[ct] = bias[ct * 16 + li];

    #pragma unroll 1
    for (int sub = 0; sub < 2; ++sub) {
        int row0 = tile * K1_ROWS + sub * 64;
        if (row0 >= N_NODES) break;          // uniform
        __syncthreads();
        {   // stage 64 node rows -> bf16 LDS
            const float4* Nv = (const float4*)nodes;
            #pragma unroll
            for (int j = 0; j < 8; ++j) {
                int fi = t + 256 * j;
                int r = row0 + (fi >> 5);
                float4 v = make_float4(0.f, 0.f, 0.f, 0.f);
                if (r < N_NODES) v = Nv[(size_t)r * 32 + (fi & 31)];
                ushort4 b;
                b.x = f2bf_rne(v.x); b.y = f2bf_rne(v.y);
                b.z = f2bf_rne(v.z); b.w = f2bf_rne(v.w);
                *(ushort4*)&At[fi >> 5][(fi & 31) * 4] = b;
            }
        }
        __syncthreads();

        short8b afr[4];
        #pragma unroll
        for (int kb = 0; kb < 4; ++kb)
            afr[kb] = *(const short8b*)&At[wv * 16 + li][kb * 32 + lg * 8];

        #pragma unroll
        for (int ct = 0; ct < 8; ++ct) {
            f32x4 acc = {0.f, 0.f, 0.f, 0.f};
            #pragma unroll
            for (int kb = 0; kb < 4; ++kb) {
                short8b bfr = *(const short8b*)&WT[ct * 16 + li][kb * 32 + lg * 8];
                acc = __builtin_amdgcn_mfma_f32_16x16x32_bf16(afr[kb], bfr, acc, 0, 0, 0);
            }
            #pragma unroll
            for (int j = 0; j < 4; ++j) {
                int r = row0 + wv * 16 + lg * 4 + j;
                if (r < N_NODES)
                    outp[(size_t)r * D + ct * 16 + li] = f2bf_rne(acc[j] + b_ct[ct]);
            }
        }
    }
}

// ---- A: proj(Ws)->hsb  ||  histogram of receivers (independent work) -------
__global__ __launch_bounds__(256, 3) void k_projS_hist(
    const float* __restrict__ nodes,
    const float* __restrict__ Ws, const float* __restrict__ bs,
    unsigned short* __restrict__ hsb,
    const int* __restrict__ receivers, int* __restrict__ deg)
{
    int bx = blockIdx.x;
    if (bx < K1_TILES) {
        proj_body(bx, nodes, Ws, bs, hsb);
    } else {
        int i = (bx - K1_TILES) * 256 + threadIdx.x;
        if (i < N_EDGES) atomicAdd(&deg[receivers[i]], 1);
    }
}

#define SCAN_CHUNK 49
__global__ __launch_bounds__(1024) void k_scan(
    const int* __restrict__ deg, int* __restrict__ rowptr, int* __restrict__ cursor)
{
    __shared__ int sm[1024];
    int t = threadIdx.x;
    int base = t * SCAN_CHUNK;
    int lsum = 0;
    #pragma unroll 4
    for (int i = 0; i < SCAN_CHUNK; ++i) {
        int idx = base + i;
        if (idx < N_NODES) lsum += deg[idx];
    }
    sm[t] = lsum;
    __syncthreads();
    for (int off = 1; off < 1024; off <<= 1) {
        int v = (t >= off) ? sm[t - off] : 0;
        __syncthreads();
        sm[t] += v;
        __syncthreads();
    }
    int run = (t > 0) ? sm[t - 1] : 0;
    for (int i = 0; i < SCAN_CHUNK; ++i) {
        int idx = base + i;
        if (idx < N_NODES) {
            rowptr[idx] = run;
            cursor[idx] = run;
            run += deg[idx];
        }
    }
    if (t == 1023) rowptr[N_NODES] = sm[1023];
}

// ---- B: proj(Wr)->hrb  ||  CSR fill (needs scan; proj_hr independent) ------
__global__ __launch_bounds__(256, 3) void k_projR_fill(
    const float* __restrict__ nodes,
    const float* __restrict__ Wr, const float* __restrict__ br,
    unsigned short* __restrict__ hrb,
    const int* __restrict__ receivers, const int* __restrict__ senders,
    int* __restrict__ cursor,
    int* __restrict__ s_csr, int* __restrict__ pos_csr)
{
    int bx = blockIdx.x;
    if (bx < K1_TILES) {
        proj_body(bx, nodes, Wr, br, hrb);
    } else {
        int i = (bx - K1_TILES) * 256 + threadIdx.x;
        if (i < N_EDGES) {
            int r = receivers[i];
            int pos = atomicAdd(&cursor[r], 1);
            s_csr[pos]  = senders[i];
            pos_csr[i]  = pos;
        }
    }
}

// ------- K2 (MFMA bf16, SEQUENTIAL edge order, scatter ex to CSR pos) --------
#define BLK_E 64
__global__ __launch_bounds__(256, 3) void k_edge_logits_mfma(
    const float* __restrict__ edges,
    const int* __restrict__ senders, const int* __restrict__ receivers,
    const int* __restrict__ pos_csr,
    const float* __restrict__ We, const float* __restrict__ be,
    const float* __restrict__ a,
    const unsigned short* __restrict__ hsb, const unsigned short* __restrict__ hrb,
    float* __restrict__ ex)
{
    __shared__ __align__(16) unsigned short WeT[D][136];    // [col][k] 34816 B
    __shared__ __align__(16) unsigned short Et[BLK_E][136]; // [edge][k] 17408 B
    int t = threadIdx.x;
    int lane = t & 63;
    int wv = t >> 6;
    int lg = lane >> 4;
    int li = lane & 15;

    #pragma unroll 8
    for (int j = 0; j < 64; ++j) {
        int idx = t + 256 * j;
        int k = idx >> 7, c = idx & 127;
        WeT[c][k] = f2bf_rne(We[idx]);
    }
    float a_h[HEADS], be_h[HEADS];
    #pragma unroll
    for (int h = 0; h < HEADS; ++h) {
        a_h[h]  = a[h * 16 + li];
        be_h[h] = be[h * 16 + li];
    }
    __syncthreads();   // WeT ready; the ONLY block barrier

    const int ntiles = N_EDGES / BLK_E;   // 12500
    const float4* Ev = (const float4*)edges;

    for (int tile = blockIdx.x; tile < ntiles; tile += gridDim.x) {
        int pb = tile * BLK_E + wv * 16;   // this wave's 16 sequential edges

        // stage 16 sequential edge rows -> bf16 LDS (1KB/instr, streaming)
        #pragma unroll
        for (int j = 0; j < 8; ++j) {
            int fi = lane + 64 * j;        // 0..511
            int rloc = fi >> 5;            // 0..15
            float4 v = Ev[(size_t)(pb + rloc) * 32 + (fi & 31)];
            ushort4 b;
            b.x = f2bf_rne(v.x); b.y = f2bf_rne(v.y);
            b.z = f2bf_rne(v.z); b.w = f2bf_rne(v.w);
            *(ushort4*)&Et[wv * 16 + rloc][(fi & 31) * 4] = b;
        }

        // streams: indices + this lane's CSR position (edge o = 4*lg+(li>>2))
        int sj[4], rj[4];
        #pragma unroll
        for (int j = 0; j < 4; ++j) {
            sj[j] = senders[pb + lg * 4 + j];
            rj[j] = receivers[pb + lg * 4 + j];
        }
        int o = 4 * lg + (li >> 2);
        int mypos = pos_csr[pb + o];

        // gathers (random, L2/L3-resident)
        unsigned short g_hs[4][HEADS], g_hr[4][HEADS];
        #pragma unroll
        for (int j = 0; j < 4; ++j) {
            const unsigned short* hsrow = hsb + (size_t)sj[j] * D + li;
            const unsigned short* hrrow = hrb + (size_t)rj[j] * D + li;
            #pragma unroll
            for (int h = 0; h < HEADS; ++h) {
                g_hs[j][h] = hsrow[h * 16];
                g_hr[j][h] = hrrow[h * 16];
            }
        }

        // intra-wave LDS write->read fence (no block barrier needed)
        asm volatile("s_waitcnt lgkmcnt(0)" ::: "memory");
        __builtin_amdgcn_sched_barrier(0);

        short8b afr[4];
        #pragma unroll
        for (int kb = 0; kb < 4; ++kb)
            afr[kb] = *(const short8b*)&Et[wv * 16 + li][kb * 32 + lg * 8];

        float hold[8];   // exp(logit) per head for this lane's edge o
        #pragma unroll
        for (int h = 0; h < HEADS; ++h) {
            f32x4 acc = {0.f, 0.f, 0.f, 0.f};
            #pragma unroll
            for (int kb = 0; kb < 4; ++kb) {
                short8b bfr = *(const short8b*)&WeT[h * 16 + li][kb * 32 + lg * 8];
                acc = __builtin_amdgcn_mfma_f32_16x16x32_bf16(afr[kb], bfr, acc, 0, 0, 0);
            }
            float pr[4];
            #pragma unroll
            for (int j = 0; j < 4; ++j) {
                float x = acc[j] + be_h[h] + bf2f(g_hs[j][h]) + bf2f(g_hr[j][h]);
                x = fmaxf(x, 0.01f * x);            // leaky relu
                pr[j] = rowsum16(x * a_h[h]);       // 4 DPP adds, no DS ops
            }
            float qa = (li & 4) ? pr[1] : pr[0];
            float qb = (li & 4) ? pr[3] : pr[2];
            hold[h] = __expf((li & 8) ? qb : qa);   // edge o = 4lg+(li>>2)
        }
        // lane packs heads {h1, h1+1} of its edge -> one scattered 8B store
        {
            float a0 = (li & 1) ? hold[2] : hold[0];
            float a1 = (li & 1) ? hold[6] : hold[4];
            float ea = (li & 2) ? a1 : a0;          // hold[h1]
            float b0 = (li & 1) ? hold[3] : hold[1];
            float b1 = (li & 1) ? hold[7] : hold[5];
            float eb = (li & 2) ? b1 : b0;          // hold[h1+1]
            int h1 = 2 * (li & 3);
            *(float2*)&ex[(size_t)mypos * HEADS + h1] = make_float2(ea, eb);
        }
        __builtin_amdgcn_wave_barrier();
    }
}

// ---------- K3: per-node gather; s_csr/ex contiguous, hs random -------------
__global__ __launch_bounds__(256) void k_gather_out(
    const int* __restrict__ rowptr, const int* __restrict__ s_csr,
    const unsigned short* __restrict__ hsb, const float* __restrict__ ex,
    float* __restrict__ out)
{
    int r = blockIdx.x * 4 + (threadIdx.x >> 6);
    int l = threadIdx.x & 63;
    int h = l >> 3;
    int beg = rowptr[r], end = rowptr[r + 1];

    float2 acc = make_float2(0.f, 0.f);
    float dsum = 0.f;
    for (int j0 = beg; j0 < end; j0 += 16) {
        int cnt = end - j0;
        int s[16]; float w[16];
        #pragma unroll
        for (int q = 0; q < 16; ++q)
            if (q < cnt) { s[q] = s_csr[j0 + q]; w[q] = ex[(size_t)(j0 + q) * HEADS + h]; }
        #pragma unroll
        for (int q = 0; q < 16; ++q)
            if (q < cnt) {
                ushort2 hv = *(const ushort2*)&hsb[(size_t)s[q] * D + 2 * l];
                acc.x += w[q] * bf2f(hv.x);
                acc.y += w[q] * bf2f(hv.y);
                dsum  += w[q];
            }
    }
    float inv = (end > beg && dsum != 0.f) ? (1.0f / dsum) : 0.f;
    acc.x *= inv; acc.y *= inv;
    *(float2*)&out[(size_t)r * D + 2 * l] = acc;
}

extern "C" void kernel_launch(void* const* d_in, const int* in_sizes, int n_in,
                              void* d_out, int out_size, void* d_ws, size_t ws_size,
                              hipStream_t stream) {
    const float* nodes     = (const float*)d_in[0];
    const float* edges     = (const float*)d_in[1];
    const int*   senders   = (const int*)d_in[2];
    const int*   receivers = (const int*)d_in[3];
    const float* Ws = (const float*)d_in[4];
    const float* bs = (const float*)d_in[5];
    const float* Wr = (const float*)d_in[6];
    const float* br = (const float*)d_in[7];
    const float* We = (const float*)d_in[8];
    const float* be = (const float*)d_in[9];
    const float* a  = (const float*)d_in[10];
    float* out = (float*)d_out;

    unsigned short* hsb = (unsigned short*)d_ws;          // 6.4M bf16
    unsigned short* hrb = hsb + (size_t)N_NODES * D;      // 6.4M bf16
    float* ex    = (float*)(hrb + (size_t)N_NODES * D);   // 6.4M f32 (CSR order)
    int* deg     = (int*)(ex + (size_t)N_EDGES * HEADS);  // 50000
    int* rowptr  = deg + N_NODES;                         // 50001
    int* cursor  = rowptr + N_NODES + 1;                  // 50000
    int* s_csr   = cursor + N_NODES;                      // 800000
    int* pos_csr = s_csr + N_EDGES;                       // 800000

    const int HIST_BLKS = N_EDGES / 256;   // 3125

    (void)hipMemsetAsync(deg, 0, N_NODES * sizeof(int), stream);
    // A: proj_hs || hist
    k_projS_hist<<<K1_TILES + HIST_BLKS, 256, 0, stream>>>(
        nodes, Ws, bs, hsb, receivers, deg);
    k_scan<<<1, 1024, 0, stream>>>(deg, rowptr, cursor);
    // B: proj_hr || fill
    k_projR_fill<<<K1_TILES + HIST_BLKS, 256, 0, stream>>>(
        nodes, Wr, br, hrb, receivers, senders, cursor, s_csr, pos_csr);
    k_edge_logits_mfma<<<2500, 256, 0, stream>>>(edges, senders, receivers, pos_csr,
                                                 We, be, a, hsb, hrb, ex);
    k_gather_out<<<N_NODES / 4, 256, 0, stream>>>(rowptr, s_csr, hsb, ex, out);
}